// Round 7
// baseline (99.092 us; speedup 1.0000x reference)
//
#include <hip/hip_runtime.h>
#include <hip/hip_bf16.h>

#define HH 512
#define WW 640
#define HW (HH*WW)
#define NT 512
#define IMPLANEP (432*8 + 8)    // img plane stride in shorts (36x12 pix, +16B pad)
#define H1PLANEP (360*8 + 8)    // h1 plane stride in shorts (36x10 pix, +16B pad)

typedef short short8  __attribute__((ext_vector_type(8)));
typedef short short4v __attribute__((ext_vector_type(4)));
typedef float f32x16  __attribute__((ext_vector_type(16)));
typedef float f32x4   __attribute__((ext_vector_type(4)));

__device__ inline short f2bf(float f) {
    __hip_bfloat16 h = __float2bfloat16(f);
    short s; __builtin_memcpy(&s, &h, 2);
    return s;
}

// ---- prep: fold BN into w1, bias as 10th tap row, transpose to MFMA layouts ----
__global__ void prep_weights(const float* __restrict__ w1, const float* __restrict__ b1,
                             const float* __restrict__ gamma, const float* __restrict__ beta,
                             const float* __restrict__ rmean, const float* __restrict__ rvar,
                             const float* __restrict__ w2,
                             short* __restrict__ ws_w1, short* __restrict__ ws_w2)
{
    int tid = blockIdx.x*blockDim.x + threadIdx.x;
    int stride = gridDim.x*blockDim.x;
    for (int i = tid; i < 4608; i += stride) {          // w1: [oc][c][t] -> [t][oc32][c16] * A_oc
        int oc = i / 144, rem = i - oc*144, c = rem / 9, t = rem - c*9;
        float a = gamma[oc] * rsqrtf(rvar[oc] + 1e-5f);
        ws_w1[t*512 + oc*16 + c] = f2bf(w1[i] * a);
    }
    for (int i = tid; i < 512; i += stride) {           // tap 9 = bias row (c==0 one-hot)
        int oc = i >> 4, c = i & 15;
        float a = gamma[oc] * rsqrtf(rvar[oc] + 1e-5f);
        float bias = beta[oc] + (b1[oc] - rmean[oc]) * a;
        ws_w1[9*512 + i] = (c == 0) ? f2bf(bias) : (short)0;
    }
    for (int i = tid; i < 4608; i += stride) {          // w2: [f][c][t] -> [t][f16][c32], f>=9 zero
        int t = i >> 9, f = (i >> 5) & 15, c = i & 31;
        float val = (f < 9) ? w2[(f*32 + c)*9 + t] : 0.f;
        ws_w2[i] = f2bf(val);
    }
}

// ---------------- main fused kernel: 512 thr (8 waves), 32x8 tile, 4 blk/CU ----------------
__launch_bounds__(NT, 8)
__global__ void fastprop_main(const float* __restrict__ depth,
                              const float* __restrict__ img,
                              const short* __restrict__ ws_w1,
                              const short* __restrict__ ws_w2,
                              float* __restrict__ out)
{
    __shared__ short s_img[2*IMPLANEP];   // [ch-plane][pix 36x12][8ch] bf16 (13856 B)
    __shared__ short s_h1 [4*H1PLANEP];   // [ch-plane][pix 36x10][8ch] bf16 (23104 B)
    __shared__ float s_depth[340];        // 34x10 replicate-clamped fp32    (1360 B)

    const int tid = threadIdx.x;

    // XCD-contiguous bijective remap: 5120 blocks = 8 XCDs x 640
    int nid = blockIdx.x;
    int oid = (nid & 7)*640 + (nid >> 3);
    int bz = oid / 1280; int rem = oid - bz*1280;
    int by = rem / 20;   int bx = rem - by*20;
    const int gy0 = by*8, gx0 = bx*32;

    const float* imgb = img   + (size_t)bz*16*HW;
    const float* dpb  = depth + (size_t)bz*HW;

    const int lane = tid & 63;
    const int wid  = tid >> 6;

    // ---- stage img tile (36x12 halo, zero at image OOB): one 16B granule/iter ----
    for (int g = tid; g < 864; g += NT) {
        int pixel = g >> 1, half = g & 1;
        int iy = pixel / 36, ix = pixel - iy*36;
        int gy = gy0 + iy - 2, gx = gx0 + ix - 2;
        bool v = ((unsigned)gy < HH) && ((unsigned)gx < WW);
        int cy = min(max(gy, 0), HH-1), cx = min(max(gx, 0), WW-1);
        const float* p = imgb + (size_t)(half*8)*HW + cy*WW + cx;
        float m = v ? 1.f : 0.f;
        short8 vv;
        #pragma unroll
        for (int c = 0; c < 8; ++c) vv[c] = f2bf(m * p[c*HW]);
        *(short8*)&s_img[half*IMPLANEP + pixel*8] = vv;
    }
    if (tid < 340) {
        int ty = tid / 34, tx = tid - ty*34;
        int gy = min(max(gy0 + ty - 1, 0), HH-1);
        int gx = min(max(gx0 + tx - 1, 0), WW-1);
        s_depth[tid] = dpb[gy*WW + gx];
    }
    __syncthreads();

    // ---- conv1 (32x32x16 MFMA, 9 taps + bias tap) -> s_h1 channel-planes ----
    {
        const int oc = lane & 31, cg = lane >> 5;
        short8 a1[10];
        #pragma unroll
        for (int t = 0; t < 10; ++t)
            a1[t] = *(const short8*)&ws_w1[t*512 + oc*16 + cg*8];
        short8 bb = (short8)0;                   // bias-tap B: one-hot 1.0 at k==0
        bb[0] = (cg == 0) ? (short)0x3F80 : (short)0;

        // tap pixel deltas {0,1,2,36,37,38,72,73,74} * 8 shorts (within a plane)
        const int OFS1[9] = {0, 8, 16, 288, 296, 304, 576, 584, 592};
        const int px = lane & 31;

        for (int g = wid; g < 12; g += 8) {
            int hp   = g*32 + px;
            int base = cg*IMPLANEP + hp*8;
            f32x16 acc;
            #pragma unroll
            for (int i = 0; i < 16; ++i) acc[i] = 0.f;
            acc = __builtin_amdgcn_mfma_f32_32x32x16_bf16(a1[9], bb, acc, 0, 0, 0);
            #pragma unroll
            for (int t = 0; t < 9; ++t)
                acc = __builtin_amdgcn_mfma_f32_32x32x16_bf16(
                         a1[t], *(const short8*)&s_img[base + OFS1[t]], acc, 0, 0, 0);

            if (hp < 360) {
                unsigned hy = (unsigned)hp / 36u;
                int hx = hp - (int)hy*36;
                int gy = gy0 + (int)hy - 1, gx = gx0 + hx - 1;
                bool inb = ((unsigned)gy < HH) && ((unsigned)gx < WW);
                #pragma unroll
                for (int q = 0; q < 4; ++q) {      // plane q = channels 8q..8q+7
                    short4v h;
                    #pragma unroll
                    for (int j = 0; j < 4; ++j) {
                        float hv = fmaxf(acc[q*4 + j], 0.f);
                        h[j] = inb ? f2bf(hv) : (short)0;
                    }
                    *(short4v*)&s_h1[q*H1PLANEP + hp*8 + 4*cg] = h;
                }
            }
        }
    }
    __syncthreads();

    // ---- conv2 (16x16x32 MFMA, 9 taps) + softmax + depth gather ----
    {
        const int fl = lane & 15, cg2 = lane >> 4;
        short8 a2[9];
        #pragma unroll
        for (int t = 0; t < 9; ++t)
            a2[t] = *(const short8*)&ws_w2[t*512 + fl*32 + cg2*8];

        // tap pixel deltas {-37,-36,-35,-1,0,1,35,36,37} * 8 shorts (within a plane)
        const int OFS2[9] = {-296, -288, -280, -8, 0, 8, 280, 288, 296};

        for (int g = wid; g < 16; g += 8) {
            int po = g*16 + fl;
            int oy = po >> 5, ox = po & 31;
            int hbase = cg2*H1PLANEP + ((oy + 1)*36 + (ox + 1))*8;
            f32x4 acc;
            #pragma unroll
            for (int i = 0; i < 4; ++i) acc[i] = 0.f;
            #pragma unroll
            for (int t = 0; t < 9; ++t)
                acc = __builtin_amdgcn_mfma_f32_16x16x32_bf16(
                         a2[t], *(const short8*)&s_h1[hbase + OFS2[t]], acc, 0, 0, 0);

            float num = 0.f, den = 0.f;
            #pragma unroll
            for (int r = 0; r < 4; ++r) {
                int f = cg2*4 + r;                 // conv2 output channel
                if (f < 9) {
                    float e = __expf(acc[r]);
                    int fy = f/3, fx = f - fy*3;   // tap (dy,dx) = (fy-1, fx-1)
                    float d = s_depth[(oy + fy)*34 + (ox + fx)];
                    den += e; num += e * d;
                }
            }
            num += __shfl_xor(num, 16); den += __shfl_xor(den, 16);
            num += __shfl_xor(num, 32); den += __shfl_xor(den, 32);
            if (cg2 == 0)
                out[(size_t)bz*HW + (size_t)(gy0 + oy)*WW + (gx0 + ox)] = num / den;
        }
    }
}

extern "C" void kernel_launch(void* const* d_in, const int* in_sizes, int n_in,
                              void* d_out, int out_size, void* d_ws, size_t ws_size,
                              hipStream_t stream) {
    const float* depth = (const float*)d_in[0];
    const float* img   = (const float*)d_in[1];
    const float* w1    = (const float*)d_in[2];
    const float* b1    = (const float*)d_in[3];
    const float* gamma = (const float*)d_in[4];
    const float* beta  = (const float*)d_in[5];
    const float* rmean = (const float*)d_in[6];
    const float* rvar  = (const float*)d_in[7];
    const float* w2    = (const float*)d_in[8];
    float* out = (float*)d_out;

    short* ws_w1 = (short*)d_ws;          // 5120 shorts (10 taps x 512)
    short* ws_w2 = ws_w1 + 5120;          // 4608 shorts

    prep_weights<<<16, 256, 0, stream>>>(w1, b1, gamma, beta, rmean, rvar, w2,
                                         ws_w1, ws_w2);
    fastprop_main<<<5120, NT, 0, stream>>>(depth, img, ws_w1, ws_w2, out);
}